// Round 12
// baseline (1131.589 us; speedup 1.0000x reference)
//
#include <hip/hip_runtime.h>

// ---------------- problem constants ----------------
constexpr int NY = 100, NX = 200;
constexpr int PML = 35;
constexpr int NYP = 170, NXP = 270;          // padded grid
constexpr int S = 2, NREC = 100, NT = 300;
constexpr float DX = 10.0f, DT = 1e-3f, DT2 = DT * DT;

// tiling: 2 shots x 16x8 tiles -> 256 blocks (one per CU)
constexpr int NTY = 16, NTX = 8;
constexpr int TY = 11, TX = 34;              // nominal tile (last row/col smaller)
constexpr int NBLKS = S * NTY * NTX;         // 256
constexpr int THREADS = 768;                 // 2 threads per cell, 12 waves/CU

// bank-friendly LDS strides (stride % 32 == 2)
constexpr int UW = 66;                       // u row stride (>= TX+16 = 50)
constexpr int UH = TY + 16;                  // 27
constexpr int PYH = TY + 8;                  // 19 rows; stride TX=34
constexpr int PXW = 66;                      // px row stride (>= cols+8 = 42)
constexpr int BYW = TY + 8;                  // 19
constexpr int BXW = TX + 8;                  // 42

// packed strips: each halo cell is 8B {float value, int tag} (single-copy atomic)
constexpr int CELLS_NS = 8 * TX;             // 272
constexpr int CELLS_WE = TY * 8;             // 88
constexpr int OFF_N = 0;
constexpr int OFF_S = CELLS_NS;              // 272
constexpr int OFF_W = 2 * CELLS_NS;          // 544
constexpr int OFF_E = 2 * CELLS_NS + CELLS_WE;  // 632
constexpr int STAGE_CELLS = 2 * CELLS_NS + 2 * CELLS_WE;  // 720 cells

typedef unsigned long long u64;

// stencil coefficients, offsets -4..4, pre-scaled by 1/dx^2 and 1/dx
__device__ __constant__ float C2D[9] = {
    (float)(-1.0/560.0/100.0), (float)(8.0/315.0/100.0), (float)(-1.0/5.0/100.0),
    (float)(8.0/5.0/100.0),    (float)(-205.0/72.0/100.0), (float)(8.0/5.0/100.0),
    (float)(-1.0/5.0/100.0),   (float)(8.0/315.0/100.0),  (float)(-1.0/560.0/100.0)};
__device__ __constant__ float C1D[9] = {
    (float)(1.0/280.0/10.0), (float)(-4.0/105.0/10.0), (float)(1.0/5.0/10.0),
    (float)(-4.0/5.0/10.0),  0.0f,                     (float)(4.0/5.0/10.0),
    (float)(-1.0/5.0/10.0),  (float)(4.0/105.0/10.0),  (float)(-1.0/280.0/10.0)};

// ---------------- agent-scope accessors (coherent at Infinity Cache) -------
__device__ __forceinline__ u64 gload64(const u64* p) {
    return __hip_atomic_load(p, __ATOMIC_RELAXED, __HIP_MEMORY_SCOPE_AGENT);
}
__device__ __forceinline__ void gstore64(u64* p, u64 v) {
    __hip_atomic_store(p, v, __ATOMIC_RELAXED, __HIP_MEMORY_SCOPE_AGENT);
}

__device__ __forceinline__ float sigma_of(int d, int n, float smax) {
    float r = fmaxf(fmaxf((float)(PML - d) / (float)PML,
                          (float)(d - (n - 1 - PML)) / (float)PML), 0.0f);
    return smax * r * r;
}

// ---------------- setup: vmax -> sigma_max ----------------
__global__ void vmax_kernel(const float* __restrict__ vp, float* __restrict__ cst) {
    __shared__ float red[256];
    float m = 0.0f;
    for (int i = threadIdx.x; i < NY * NX; i += 256) m = fmaxf(m, vp[i]);
    red[threadIdx.x] = m;
    __syncthreads();
    for (int s2 = 128; s2 > 0; s2 >>= 1) {
        if (threadIdx.x < s2) red[threadIdx.x] = fmaxf(red[threadIdx.x], red[threadIdx.x + s2]);
        __syncthreads();
    }
    if (threadIdx.x == 0)
        cst[0] = 3.0f * red[0] * logf(1000.0f) / (2.0f * PML * DX);
}

// -- persistent kernel: interior-first, late halo absorb, early publish ------
__global__ __launch_bounds__(THREADS) void persist_kernel(
    const float* __restrict__ vp, const float* __restrict__ src,
    const int* __restrict__ src_loc, const int* __restrict__ rec_loc,
    float* __restrict__ out, u64* __restrict__ stage,
    const float* __restrict__ cst) {

    __shared__ float uS[2][UH * UW];       // u(t) / u(t-1)->u(t+1), swap each step
    __shared__ float pyS[2][PYH * TX];     // py double buffer
    __shared__ float pxS[2][TY * PXW];     // px double buffer
    __shared__ float byS[BYW], bymS[BYW], bxS[BXW], bxmS[BXW];
    __shared__ float srcS[NT];             // this shot's source wavelet

    const int tid = threadIdx.x;
    const int bid = blockIdx.x;
    const int sh  = bid / (NTY * NTX);
    const int tr  = bid - sh * (NTY * NTX);
    const int tyi = tr / NTX, txi = tr - tyi * NTX;
    const int y0 = tyi * TY, x0 = txi * TX;
    const int rows = min(TY, NYP - y0), cols = min(TX, NXP - x0);
    const float smax = cst[0];

    // zero LDS state (domain-boundary halos stay 0 forever)
    for (int i = tid; i < 2 * UH * UW; i += THREADS) ((float*)uS)[i] = 0.0f;
    for (int i = tid; i < 2 * PYH * TX; i += THREADS) ((float*)pyS)[i] = 0.0f;
    for (int i = tid; i < 2 * TY * PXW; i += THREADS) ((float*)pxS)[i] = 0.0f;

    if (tid < BYW) {
        int yy = y0 - 4 + tid;
        if (yy >= 0 && yy < NYP) {
            float b = __expf(-sigma_of(yy, NYP, smax) * DT);
            byS[tid] = b; bymS[tid] = b - 1.0f;
        } else { byS[tid] = 0.0f; bymS[tid] = 0.0f; }
    }
    if (tid < BXW) {
        int xx = x0 - 4 + tid;
        if (xx >= 0 && xx < NXP) {
            float b = __expf(-sigma_of(xx, NXP, smax) * DT);
            bxS[tid] = b; bxmS[tid] = b - 1.0f;
        } else { bxS[tid] = 0.0f; bxmS[tid] = 0.0f; }
    }

    // lane-pair cell mapping: threads 2c (role 0: column) / 2c+1 (role 1: row)
    const int role = tid & 1;
    const int cell = tid >> 1;
    const bool hasTask = (tid < 2 * rows * cols);
    const int y = hasTask ? cell / cols : 0;
    const int x = hasTask ? cell - y * cols : 0;
    // interior tap window for this role: tap j interior iff ivLo <= j <= ivHi
    const int ivLo = role ? (8 - x) : (8 - y);
    const int ivHi = role ? (7 + cols - x) : (7 + rows - y);

    // per-thread t-invariant physics coefficients (role 0 only)
    float e_r = 0.0f, d_r = 0.0f, Av_r = 0.0f, Bv_r = 0.0f;
    if (hasTask && role == 0) {
        int gy = y0 + y, gx = x0 + x;
        int vy = min(max(gy - PML, 0), NY - 1), vx = min(max(gx - PML, 0), NX - 1);
        float v = vp[vy * NX + vx];
        e_r = DT2 * v * v;
        float syv = sigma_of(gy, NYP, smax), sxv = sigma_of(gx, NXP, smax);
        d_r  = 1.0f / (1.0f + 0.5f * (syv + sxv) * DT);
        Av_r = 2.0f - syv * sxv * DT2;
        Bv_r = 1.0f - 0.5f * (syv + sxv) * DT;
    }

    // source (NSRC == 1 per shot); stage wavelet into LDS
    const int sy = src_loc[sh * 2 + 0] + PML, sx = src_loc[sh * 2 + 1] + PML;
    const bool ownSrc = (sy >= y0 && sy < y0 + rows && sx >= x0 && sx < x0 + cols);
    const bool isSrc = hasTask && (role == 0) && ownSrc &&
                       (y == sy - y0) && (x == sx - x0);
    if (ownSrc)
        for (int i = tid; i < NT; i += THREADS) srcS[i] = src[sh * NT + i];

    // receiver: thread tid handles global receiver tid (<=1 per thread)
    int recLds = -1, recOut = 0;
    if (tid < S * NREC) {
        int rs = tid / NREC, rr2 = tid - rs * NREC;
        int ry = rec_loc[(rs * NREC + rr2) * 2 + 0] + PML;
        int rx = rec_loc[(rs * NREC + rr2) * 2 + 1] + PML;
        if (rs == sh && ry >= y0 && ry < y0 + rows && rx >= x0 && rx < x0 + cols) {
            recLds = (ry - y0 + 8) * UW + (rx - x0 + 8);
            recOut = rs * NT * NREC + rr2;
        }
    }

    const int bN = (tyi > 0)       ? bid - NTX : -1;
    const int bS = (tyi < NTY - 1) ? bid + NTX : -1;
    const int bW = (txi > 0)       ? bid - 1   : -1;
    const int bE = (txi < NTX - 1) ? bid + 1   : -1;

    const int nNS = 8 * cols, nWE = rows * 8;
    const int nTot = 2 * nNS + 2 * nWE;       // <= 720 <= THREADS

    // ---- single halo-read descriptor per thread (t-invariant) ----
    int hLds = -1, hSrc = 0;
    if (tid < nTot) {
        int j = tid, nb = -1, o = 0, lds = -1;
        if (j < nNS) {                         // from N neighbor's S strip
            nb = bN;
            int r2 = j / cols, c2 = j - r2 * cols;
            o = OFF_S + r2 * TX + c2;          // N nb always has rows==TY>=8
            lds = r2 * UW + 8 + c2;
        } else if ((j -= nNS) < nNS) {         // from S neighbor's N strip
            nb = bS;
            int r2 = j / cols, c2 = j - r2 * cols;
            if (nb >= 0) {
                int rowsS = min(TY, NYP - (y0 + TY));
                if (r2 >= rowsS) nb = -1;      // out-of-domain: stays 0
            }
            o = OFF_N + r2 * TX + c2;
            lds = (8 + rows + r2) * UW + 8 + c2;
        } else if ((j -= nNS) < nWE) {         // from W neighbor's E strip
            nb = bW;
            o = OFF_E + j;
            lds = (8 + (j >> 3)) * UW + (j & 7);
        } else {                               // from E neighbor's W strip
            j -= nWE;
            nb = bE;
            o = OFF_W + j;
            lds = (8 + (j >> 3)) * UW + 8 + cols + (j & 7);
        }
        if (nb >= 0) { hLds = lds; hSrc = nb * 2 * STAGE_CELLS + o; }
    }
    const bool nv = (hLds >= 0);
    const u64* sA = stage + hSrc;

    // ---- strip-push cell offsets (role 0 only, t-invariant) ----
    int aN = -1, aS = -1, aW = -1, aE = -1;
    if (hasTask && role == 0) {
        if (y < 8)          aN = OFF_N + y * TX + x;
        if (y >= rows - 8)  aS = OFF_S + (y - (rows - 8)) * TX + x;
        if (x < 8)          aW = OFF_W + y * 8 + x;
        if (x >= cols - 8)  aE = OFF_E + y * 8 + (x - (cols - 8));
    }

    // prologue: publish u(0)=0 cells with tag=1 into parity-0 slot
    {
        const u64 PK0 = ((u64)1 << 32);
        u64* s0 = stage + (size_t)(bid * 2 + 0) * STAGE_CELLS;
        if (aN >= 0) gstore64(s0 + aN, PK0);
        if (aS >= 0) gstore64(s0 + aS, PK0);
        if (aW >= 0) gstore64(s0 + aW, PK0);
        if (aE >= 0) gstore64(s0 + aE, PK0);
    }
    __syncthreads();

    // per-thread CPML recursion coefficients -> registers (shortens the tail)
    float bbr[9], bbmr[9];
#pragma unroll
    for (int j = 0; j < 9; j++) {
        bbr[j]  = hasTask ? (role ? bxS[x + j]  : byS[y + j])  : 0.0f;
        bbmr[j] = hasTask ? (role ? bxmS[x + j] : bymS[y + j]) : 0.0f;
    }

    // prefetch for t=0 (parity-0 slot)
    u64 pf = nv ? gload64(sA) : 0;

    float u_curr = 0.0f, u_prev = 0.0f;        // this cell's u(t), u(t-1)

    int pa = 0;
    for (int t = 0; t < NT; t++) {
        const int par = t & 1;                 // slot holding u(t) strips
        float* uCur = uS[pa];
        float* uN   = uS[pa ^ 1];
        const float* pyO = pyS[pa];
        float*       pyN = pyS[pa ^ 1];
        const float* pxO = pxS[pa];
        float*       pxN = pxS[pa ^ 1];

        __syncthreads();                       // B1: prev writes visible

        // receivers sample u(t) = un(t-1)
        if (t > 0 && recLds >= 0) out[recOut + (t - 1) * NREC] = uCur[recLds];

        // ---- phase A: interior-only partial sums (halo-independent) ----
        float pnS[9], pOv[9];
        float d2S = 0.0f;
        if (hasTask) {
            const float* uSrc = role ? &uCur[(8 + y) * UW + x]
                                     : &uCur[y * UW + 8 + x];
            const int uStr = role ? 1 : UW;
            const float* pSrc = role ? &pxO[y * PXW + x] : &pyO[y * TX + x];
            const int pStr = role ? 1 : TX;

            float up[17];
            up[8] = u_curr;
#pragma unroll
            for (int j = 0; j < 17; j++) {
                if (j == 8) continue;
                up[j] = (j >= ivLo && j <= ivHi) ? uSrc[j * uStr] : 0.0f;
            }
#pragma unroll
            for (int j = 0; j < 9; j++) pOv[j] = pSrc[j * pStr];

#pragma unroll
            for (int jj = 0; jj < 9; jj++) {
                float a = 0.0f, b = 0.0f;
#pragma unroll
                for (int k = 0; k < 4; k++) {
                    a = fmaf(C1D[k],     up[jj + k],     a);
                    b = fmaf(C1D[k + 5], up[jj + k + 5], b);
                }
                pnS[jj] = a + b;
            }
#pragma unroll
            for (int k = 0; k < 9; k++) d2S = fmaf(C2D[k], up[4 + k], d2S);
        }

        // ---- phase B: spin (latency hidden under phase A) + halo LDS write
        if (nv) {
            const int need = t + 1;
            const u64* sp = sA + (size_t)par * STAGE_CELLS;
            while ((int)(pf >> 32) < need) pf = gload64(sp);
            uCur[hLds] = __uint_as_float((unsigned)pf);
        }
        __syncthreads();                       // B2: halo visible

        // ---- phase C: fold halo taps, finish, publish ASAP ----
        u64* sb = stage + (size_t)(bid * 2 + (par ^ 1)) * STAGE_CELLS;
        if (hasTask) {
            const float* uSrc = role ? &uCur[(8 + y) * UW + x]
                                     : &uCur[y * UW + 8 + x];
            const int uStr = role ? 1 : UW;
#pragma unroll
            for (int j = 0; j < 17; j++) {
                if (j == 8) continue;
                if (j < ivLo || j > ivHi) {    // halo tap (domain edge reads 0)
                    float h = uSrc[j * uStr];
                    if (j >= 4 && j <= 12) d2S = fmaf(C2D[j - 4], h, d2S);
#pragma unroll
                    for (int jj = (j > 8 ? j - 8 : 0);
                         jj <= (j < 8 ? j : 8); jj++) {
                        if (jj == j - 4) continue;   // C1D[4] == 0
                        pnS[jj] = fmaf(C1D[j - jj], h, pnS[jj]);
                    }
                }
            }
            float pn[9];
#pragma unroll
            for (int j = 0; j < 9; j++)
                pn[j] = fmaf(bbr[j], pOv[j], bbmr[j] * pnS[j]);
            float d1p = 0.0f;
#pragma unroll
            for (int k = 0; k < 9; k++)
                if (k != 4) d1p = fmaf(C1D[k], pn[k], d1p);

            const float partial = d2S + d1p;
            const float other = __shfl_xor(partial, 1);  // pair exchange

            float unv = 0.0f;
            if (role == 0) {
                const float lap = partial + other;
                const float f = isSrc ? srcS[t] : 0.0f;
                unv = (Av_r * u_curr - Bv_r * u_prev + e_r * (lap + f)) * d_r;
                // publish immediately: {u(t+1), tag=t+2}
                const u64 pk = ((u64)(unsigned)(t + 2) << 32) |
                               (u64)__float_as_uint(unv);
                if (aN >= 0) gstore64(sb + aN, pk);
                if (aS >= 0) gstore64(sb + aS, pk);
                if (aW >= 0) gstore64(sb + aW, pk);
                if (aE >= 0) gstore64(sb + aE, pk);
            }
            const float got = __shfl_xor(unv, 1);        // unv to role 1
            const float u_new = role ? got : unv;

            // LDS state writes (after publish; next iter reads after B1)
            float* pDst = role ? pxN : pyN;
            pDst[role ? (y * PXW + x + 4) : ((y + 4) * TX + x)] = pn[4];
            const int lo = role ? x : y;
            const int hiLim = role ? cols : rows;
            if (lo < 4)
                pDst[role ? (y * PXW + x) : (y * TX + x)] = pn[0];
            if (lo >= hiLim - 4)
                pDst[role ? (y * PXW + x + 8) : ((y + 8) * TX + x)] = pn[8];
            if (role == 0) uN[(8 + y) * UW + 8 + x] = unv;
            u_prev = u_curr; u_curr = u_new;
        }

        // ---- prefetch next slot (overlaps MALL RT with loop tail) ----
        if (nv) pf = gload64(sA + (size_t)(par ^ 1) * STAGE_CELLS);

        pa ^= 1;
    }

    // epilogue: sample the last wavefield u(NT) = un(NT-1)
    __syncthreads();
    if (recLds >= 0) out[recOut + (NT - 1) * NREC] = uS[pa][recLds];
}

// ---------------- host launch ----------------
extern "C" void kernel_launch(void* const* d_in, const int* in_sizes, int n_in,
                              void* d_out, int out_size, void* d_ws, size_t ws_size,
                              hipStream_t stream) {
    const float* vp = (const float*)d_in[0];
    const float* src = (const float*)d_in[1];
    const int* src_loc = (const int*)d_in[2];
    const int* rec_loc = (const int*)d_in[3];
    float* out = (float*)d_out;

    float* ws = (float*)d_ws;
    float* cst = ws;                           // 32 floats (keeps stage 8B-aligned)
    u64* stage = (u64*)(ws + 32);              // NBLKS*2*STAGE_CELLS packed cells

    // zero cst + stage (tags=0; prologue publishes tag=1 cells into slot 0)
    hipMemsetAsync(d_ws, 0,
                   (size_t)32 * sizeof(float) +
                   (size_t)NBLKS * 2 * STAGE_CELLS * sizeof(u64),
                   stream);
    vmax_kernel<<<1, 256, 0, stream>>>(vp, cst);
    persist_kernel<<<NBLKS, THREADS, 0, stream>>>(
        vp, src, src_loc, rec_loc, out, stage, cst);
}

// Round 13
// 782.674 us; speedup vs baseline: 1.4458x; 1.4458x over previous
//
#include <hip/hip_runtime.h>

// ---------------- problem constants ----------------
constexpr int NY = 100, NX = 200;
constexpr int PML = 35;
constexpr int NYP = 170, NXP = 270;          // padded grid
constexpr int S = 2, NREC = 100, NT = 300;
constexpr float DX = 10.0f, DT = 1e-3f, DT2 = DT * DT;

// tiling: 2 shots x 16x8 tiles -> 256 blocks (one per CU)
constexpr int NTY = 16, NTX = 8;
constexpr int TY = 11, TX = 34;              // nominal tile (last row/col smaller)
constexpr int NBLKS = S * NTY * NTX;         // 256
constexpr int THREADS = 768;                 // 2 threads per cell, 12 waves/CU

// dual-orientation LDS (odd strides -> full bank spread; every hot access is
// base[j] with compile-time j -> ds_read offset: immediates, no address VALU)
constexpr int UTS = 35;                      // uT stride: uT[x][y+8], slots 0..26
constexpr int UTSZ = TX * UTS;               // 1190
constexpr int URS = 51;                      // uR stride: uR[y][x+8], slots 0..49
constexpr int URSZ = TY * URS;               // 561
constexpr int PTS = 19;                      // pyT stride: pyT[x][y+4], slots 0..18
constexpr int PTSZ = TX * PTS;               // 646
constexpr int PXS = 43;                      // pxR stride: pxR[y][x+4], slots 0..41
constexpr int PXSZ = TY * PXS;               // 473
constexpr int BYW = TY + 8;                  // 19
constexpr int BXW = TX + 8;                  // 42

// packed strips: each halo cell is 8B {float value, int tag} (single-copy atomic)
constexpr int CELLS_NS = 8 * TX;             // 272
constexpr int CELLS_WE = TY * 8;             // 88
constexpr int OFF_N = 0;
constexpr int OFF_S = CELLS_NS;              // 272
constexpr int OFF_W = 2 * CELLS_NS;          // 544
constexpr int OFF_E = 2 * CELLS_NS + CELLS_WE;  // 632
constexpr int STAGE_CELLS = 2 * CELLS_NS + 2 * CELLS_WE;  // 720 cells

typedef unsigned long long u64;

// stencil coefficients, offsets -4..4, pre-scaled by 1/dx^2 and 1/dx
__device__ __constant__ float C2D[9] = {
    (float)(-1.0/560.0/100.0), (float)(8.0/315.0/100.0), (float)(-1.0/5.0/100.0),
    (float)(8.0/5.0/100.0),    (float)(-205.0/72.0/100.0), (float)(8.0/5.0/100.0),
    (float)(-1.0/5.0/100.0),   (float)(8.0/315.0/100.0),  (float)(-1.0/560.0/100.0)};
__device__ __constant__ float C1D[9] = {
    (float)(1.0/280.0/10.0), (float)(-4.0/105.0/10.0), (float)(1.0/5.0/10.0),
    (float)(-4.0/5.0/10.0),  0.0f,                     (float)(4.0/5.0/10.0),
    (float)(-1.0/5.0/10.0),  (float)(4.0/105.0/10.0),  (float)(-1.0/280.0/10.0)};

// ---------------- agent-scope accessors (coherent at Infinity Cache) -------
__device__ __forceinline__ u64 gload64(const u64* p) {
    return __hip_atomic_load(p, __ATOMIC_RELAXED, __HIP_MEMORY_SCOPE_AGENT);
}
__device__ __forceinline__ void gstore64(u64* p, u64 v) {
    __hip_atomic_store(p, v, __ATOMIC_RELAXED, __HIP_MEMORY_SCOPE_AGENT);
}

__device__ __forceinline__ float sigma_of(int d, int n, float smax) {
    float r = fmaxf(fmaxf((float)(PML - d) / (float)PML,
                          (float)(d - (n - 1 - PML)) / (float)PML), 0.0f);
    return smax * r * r;
}

// ---------------- setup: vmax -> sigma_max ----------------
__global__ void vmax_kernel(const float* __restrict__ vp, float* __restrict__ cst) {
    __shared__ float red[256];
    float m = 0.0f;
    for (int i = threadIdx.x; i < NY * NX; i += 256) m = fmaxf(m, vp[i]);
    red[threadIdx.x] = m;
    __syncthreads();
    for (int s2 = 128; s2 > 0; s2 >>= 1) {
        if (threadIdx.x < s2) red[threadIdx.x] = fmaxf(red[threadIdx.x], red[threadIdx.x + s2]);
        __syncthreads();
    }
    if (threadIdx.x == 0)
        cst[0] = 3.0f * red[0] * logf(1000.0f) / (2.0f * PML * DX);
}

// -- persistent kernel: lane-pair roles, dual-orientation LDS, reg history ---
__global__ __launch_bounds__(THREADS) void persist_kernel(
    const float* __restrict__ vp, const float* __restrict__ src,
    const int* __restrict__ src_loc, const int* __restrict__ rec_loc,
    float* __restrict__ out, u64* __restrict__ stage,
    const float* __restrict__ cst) {

    __shared__ float uT[2][UTSZ];          // u, x-major (column role reads)
    __shared__ float uR[2][URSZ];          // u, y-major (row role reads)
    __shared__ float pyT[2][PTSZ];         // py, x-major
    __shared__ float pxR[2][PXSZ];         // px, y-major
    __shared__ float byS[BYW], bymS[BYW], bxS[BXW], bxmS[BXW];
    __shared__ float srcS[NT];             // this shot's source wavelet

    const int tid = threadIdx.x;
    const int bid = blockIdx.x;
    const int sh  = bid / (NTY * NTX);
    const int tr  = bid - sh * (NTY * NTX);
    const int tyi = tr / NTX, txi = tr - tyi * NTX;
    const int y0 = tyi * TY, x0 = txi * TX;
    const int rows = min(TY, NYP - y0), cols = min(TX, NXP - x0);
    const float smax = cst[0];

    // zero LDS state (domain-boundary halos stay 0 forever)
    for (int i = tid; i < 2 * UTSZ; i += THREADS) ((float*)uT)[i] = 0.0f;
    for (int i = tid; i < 2 * URSZ; i += THREADS) ((float*)uR)[i] = 0.0f;
    for (int i = tid; i < 2 * PTSZ; i += THREADS) ((float*)pyT)[i] = 0.0f;
    for (int i = tid; i < 2 * PXSZ; i += THREADS) ((float*)pxR)[i] = 0.0f;

    if (tid < BYW) {
        int yy = y0 - 4 + tid;
        if (yy >= 0 && yy < NYP) {
            float b = __expf(-sigma_of(yy, NYP, smax) * DT);
            byS[tid] = b; bymS[tid] = b - 1.0f;
        } else { byS[tid] = 0.0f; bymS[tid] = 0.0f; }
    }
    if (tid < BXW) {
        int xx = x0 - 4 + tid;
        if (xx >= 0 && xx < NXP) {
            float b = __expf(-sigma_of(xx, NXP, smax) * DT);
            bxS[tid] = b; bxmS[tid] = b - 1.0f;
        } else { bxS[tid] = 0.0f; bxmS[tid] = 0.0f; }
    }

    // lane-pair cell mapping: threads 2c (role 0: column) / 2c+1 (role 1: row)
    const int role = tid & 1;
    const int cell = tid >> 1;
    const bool hasTask = (tid < 2 * rows * cols);
    const int y = hasTask ? cell / cols : 0;
    const int x = hasTask ? cell - y * cols : 0;

    // per-thread t-invariant physics coefficients (role 0 only)
    float e_r = 0.0f, d_r = 0.0f, Av_r = 0.0f, Bv_r = 0.0f;
    if (hasTask && role == 0) {
        int gy = y0 + y, gx = x0 + x;
        int vy = min(max(gy - PML, 0), NY - 1), vx = min(max(gx - PML, 0), NX - 1);
        float v = vp[vy * NX + vx];
        e_r = DT2 * v * v;
        float syv = sigma_of(gy, NYP, smax), sxv = sigma_of(gx, NXP, smax);
        d_r  = 1.0f / (1.0f + 0.5f * (syv + sxv) * DT);
        Av_r = 2.0f - syv * sxv * DT2;
        Bv_r = 1.0f - 0.5f * (syv + sxv) * DT;
    }

    // source (NSRC == 1 per shot); stage wavelet into LDS
    const int sy = src_loc[sh * 2 + 0] + PML, sx = src_loc[sh * 2 + 1] + PML;
    const bool ownSrc = (sy >= y0 && sy < y0 + rows && sx >= x0 && sx < x0 + cols);
    const bool isSrc = hasTask && (role == 0) && ownSrc &&
                       (y == sy - y0) && (x == sx - x0);
    if (ownSrc)
        for (int i = tid; i < NT; i += THREADS) srcS[i] = src[sh * NT + i];

    // receiver: thread tid handles global receiver tid (<=1 per thread)
    int recLds = -1, recOut = 0;
    if (tid < S * NREC) {
        int rs = tid / NREC, rr2 = tid - rs * NREC;
        int ry = rec_loc[(rs * NREC + rr2) * 2 + 0] + PML;
        int rx = rec_loc[(rs * NREC + rr2) * 2 + 1] + PML;
        if (rs == sh && ry >= y0 && ry < y0 + rows && rx >= x0 && rx < x0 + cols) {
            recLds = (ry - y0) * URS + (rx - x0 + 8);    // in uR (y-major)
            recOut = rs * NT * NREC + rr2;
        }
    }

    const int bN = (tyi > 0)       ? bid - NTX : -1;
    const int bS = (tyi < NTY - 1) ? bid + NTX : -1;
    const int bW = (txi > 0)       ? bid - 1   : -1;
    const int bE = (txi < NTX - 1) ? bid + 1   : -1;

    const int nNS = 8 * cols, nWE = rows * 8;
    const int nTot = 2 * nNS + 2 * nWE;       // <= 720 <= THREADS

    // ---- single halo-read descriptor per thread (t-invariant) ----
    // N/S halo rows feed the column role -> uT; W/E cols -> uR.
    int hOff = -1, hSrc = 0, hTgt = 0;
    if (tid < nTot) {
        int j = tid, nb = -1, o = 0, off = -1, tgt = 0;
        if (j < nNS) {                         // from N neighbor's S strip
            nb = bN;
            int r2 = j / cols, c2 = j - r2 * cols;
            o = OFF_S + r2 * TX + c2;          // N nb always has rows==TY>=8
            off = c2 * UTS + r2; tgt = 0;
        } else if ((j -= nNS) < nNS) {         // from S neighbor's N strip
            nb = bS;
            int r2 = j / cols, c2 = j - r2 * cols;
            if (nb >= 0) {
                int rowsS = min(TY, NYP - (y0 + TY));
                if (r2 >= rowsS) nb = -1;      // out-of-domain: stays 0
            }
            o = OFF_N + r2 * TX + c2;
            off = c2 * UTS + (8 + rows + r2); tgt = 0;
        } else if ((j -= nNS) < nWE) {         // from W neighbor's E strip
            nb = bW;
            o = OFF_E + j;
            off = (j >> 3) * URS + (j & 7); tgt = 1;
        } else {                               // from E neighbor's W strip
            j -= nWE;
            nb = bE;
            o = OFF_W + j;
            off = (j >> 3) * URS + 8 + cols + (j & 7); tgt = 1;
        }
        if (nb >= 0) { hOff = off; hTgt = tgt; hSrc = nb * 2 * STAGE_CELLS + o; }
    }
    const bool nv = (hOff >= 0);
    const u64* sA = stage + hSrc;

    // ---- strip-push cell offsets (role 0 only, t-invariant) ----
    int aN = -1, aS = -1, aW = -1, aE = -1;
    if (hasTask && role == 0) {
        if (y < 8)          aN = OFF_N + y * TX + x;
        if (y >= rows - 8)  aS = OFF_S + (y - (rows - 8)) * TX + x;
        if (x < 8)          aW = OFF_W + y * 8 + x;
        if (x >= cols - 8)  aE = OFF_E + y * 8 + (x - (cols - 8));
    }

    // prologue: publish u(0)=0 cells with tag=1 into parity-0 slot
    {
        const u64 PK0 = ((u64)1 << 32);
        u64* s0 = stage + (size_t)(bid * 2 + 0) * STAGE_CELLS;
        if (aN >= 0) gstore64(s0 + aN, PK0);
        if (aS >= 0) gstore64(s0 + aS, PK0);
        if (aW >= 0) gstore64(s0 + aW, PK0);
        if (aE >= 0) gstore64(s0 + aE, PK0);
    }
    __syncthreads();

    // per-thread CPML recursion coefficients -> registers (-18 LDS reads/step)
    float bbr[9], bbmr[9];
#pragma unroll
    for (int j = 0; j < 9; j++) {
        bbr[j]  = hasTask ? (role ? bxS[x + j]  : byS[y + j])  : 0.0f;
        bbmr[j] = hasTask ? (role ? bxmS[x + j] : bymS[y + j]) : 0.0f;
    }

    // prefetch for t=0 (parity-0 slot)
    u64 pf = nv ? gload64(sA) : 0;

    float u_curr = 0.0f, u_prev = 0.0f;        // this cell's u(t), u(t-1)

    int pa = 0;
    for (int t = 0; t < NT; t++) {
        const int par = t & 1;                 // slot holding u(t) strips
        float* uTc = uT[pa];       float* uRc = uR[pa];
        float* uTn = uT[pa ^ 1];   float* uRn = uR[pa ^ 1];
        const float* pyO = pyT[pa]; float* pyN = pyT[pa ^ 1];
        const float* pxO = pxR[pa]; float* pxN = pxR[pa ^ 1];

        // ---- 1. spin on prefetched packed cell; write halo to LDS ----
        if (nv) {
            const int need = t + 1;
            const u64* sp = sA + (size_t)par * STAGE_CELLS;
            while ((int)(pf >> 32) < need) pf = gload64(sp);
            (hTgt ? uRc : uTc)[hOff] = __uint_as_float((unsigned)pf);
        }
        __syncthreads();                       // the ONLY barrier per step

        // ---- 2. receivers sample u(t) = un(t-1) ----
        if (t > 0 && recLds >= 0) out[recOut + (t - 1) * NREC] = uRc[recLds];

        // ---- 3. role-split fused compute + early publish ----
        u64* sb = stage + (size_t)(bid * 2 + (par ^ 1)) * STAGE_CELLS;
        if (hasTask) {
            // all hot LDS accesses: base[j], j compile-time -> offset: immediates
            const float* uSrc = role ? &uRc[y * URS + x] : &uTc[x * UTS + y];
            const float* pSrc = role ? &pxO[y * PXS + x] : &pyO[x * PTS + y];
            float* pDst = role ? &pxN[y * PXS + x] : &pyN[x * PTS + y];
            float* uDst = role ? &uRn[y * URS + x + 8] : &uTn[x * UTS + y + 8];

            float up[17];
#pragma unroll
            for (int j = 0; j < 17; j++)
                up[j] = (j == 8) ? u_curr : uSrc[j];

            float pn[9];
#pragma unroll
            for (int j = 0; j < 9; j++) {
                float d1a = 0.0f, d1b = 0.0f;
#pragma unroll
                for (int k = 0; k < 4; k++) {
                    d1a = fmaf(C1D[k],     up[j + k],     d1a);
                    d1b = fmaf(C1D[k + 5], up[j + k + 5], d1b);
                }
                pn[j] = fmaf(bbr[j], pSrc[j], bbmr[j] * (d1a + d1b));
            }

            float d2 = 0.0f, d1p = 0.0f;
#pragma unroll
            for (int k = 0; k < 9; k++) {
                d2 = fmaf(C2D[k], up[4 + k], d2);
                if (k != 4) d1p = fmaf(C1D[k], pn[k], d1p);
            }
            const float partial = d2 + d1p;
            const float other = __shfl_xor(partial, 1);  // pair exchange

            float unv = 0.0f;
            if (role == 0) {
                const float lap = partial + other;
                const float f = isSrc ? srcS[t] : 0.0f;
                unv = (Av_r * u_curr - Bv_r * u_prev + e_r * (lap + f)) * d_r;
                // early packed publish: {u(t+1), tag=t+2} from register
                const u64 pk = ((u64)(unsigned)(t + 2) << 32) |
                               (u64)__float_as_uint(unv);
                if (aN >= 0) gstore64(sb + aN, pk);
                if (aS >= 0) gstore64(sb + aS, pk);
                if (aW >= 0) gstore64(sb + aW, pk);
                if (aE >= 0) gstore64(sb + aE, pk);
            }
            const float got = __shfl_xor(unv, 1);        // unv to role 1
            const float u_new = role ? got : unv;

            uDst[0] = u_new;                   // each role updates its array
            pDst[4] = pn[4];
            const int lo = role ? x : y;
            const int hiLim = role ? cols : rows;
            if (lo < 4)          pDst[0] = pn[0];
            if (lo >= hiLim - 4) pDst[8] = pn[8];

            u_prev = u_curr; u_curr = u_new;
        }

        // ---- 4. prefetch next slot (overlaps MALL RT with loop tail) ----
        if (nv) pf = gload64(sA + (size_t)(par ^ 1) * STAGE_CELLS);

        pa ^= 1;
    }

    // epilogue: sample the last wavefield u(NT) = un(NT-1)
    __syncthreads();
    if (recLds >= 0) out[recOut + (NT - 1) * NREC] = uR[pa][recLds];
}

// ---------------- host launch ----------------
extern "C" void kernel_launch(void* const* d_in, const int* in_sizes, int n_in,
                              void* d_out, int out_size, void* d_ws, size_t ws_size,
                              hipStream_t stream) {
    const float* vp = (const float*)d_in[0];
    const float* src = (const float*)d_in[1];
    const int* src_loc = (const int*)d_in[2];
    const int* rec_loc = (const int*)d_in[3];
    float* out = (float*)d_out;

    float* ws = (float*)d_ws;
    float* cst = ws;                           // 32 floats (keeps stage 8B-aligned)
    u64* stage = (u64*)(ws + 32);              // NBLKS*2*STAGE_CELLS packed cells

    // zero cst + stage (tags=0; prologue publishes tag=1 cells into slot 0)
    hipMemsetAsync(d_ws, 0,
                   (size_t)32 * sizeof(float) +
                   (size_t)NBLKS * 2 * STAGE_CELLS * sizeof(u64),
                   stream);
    vmax_kernel<<<1, 256, 0, stream>>>(vp, cst);
    persist_kernel<<<NBLKS, THREADS, 0, stream>>>(
        vp, src, src_loc, rec_loc, out, stage, cst);
}

// Round 14
// 714.534 us; speedup vs baseline: 1.5837x; 1.0954x over previous
//
#include <hip/hip_runtime.h>

// ---------------- problem constants ----------------
constexpr int NY = 100, NX = 200;
constexpr int PML = 35;
constexpr int NYP = 170, NXP = 270;          // padded grid
constexpr int S = 2, NREC = 100, NT = 300;
constexpr float DX = 10.0f, DT = 1e-3f, DT2 = DT * DT;

// tiling: 2 shots x 16x8 tiles -> 256 blocks (one per CU)
constexpr int NTY = 16, NTX = 8;
constexpr int TY = 11, TX = 34;              // nominal tile (last row/col smaller)
constexpr int NBLKS = S * NTY * NTX;         // 256
constexpr int THREADS = 768;                 // 2 threads per cell, 12 waves/CU

// dual-orientation LDS (odd strides -> full bank spread; every hot access is
// base[j] with compile-time j -> ds_read offset: immediates, no address VALU)
constexpr int UTS = 35;                      // uT stride: uT[x][y+8], slots 0..26
constexpr int UTSZ = TX * UTS;               // 1190
constexpr int URS = 51;                      // uR stride: uR[y][x+8], slots 0..49
constexpr int URSZ = TY * URS;               // 561
constexpr int PTS = 19;                      // pyT stride: pyT[x][y+4], slots 0..18
constexpr int PTSZ = TX * PTS;               // 646
constexpr int PXS = 43;                      // pxR stride: pxR[y][x+4], slots 0..41
constexpr int PXSZ = TY * PXS;               // 473
constexpr int BYW = TY + 8;                  // 19
constexpr int BXW = TX + 8;                  // 42

// packed strips: each halo cell is 8B {float value, int tag} (single-copy atomic)
constexpr int CELLS_NS = 8 * TX;             // 272
constexpr int CELLS_WE = TY * 8;             // 88
constexpr int OFF_N = 0;
constexpr int OFF_S = CELLS_NS;              // 272
constexpr int OFF_W = 2 * CELLS_NS;          // 544
constexpr int OFF_E = 2 * CELLS_NS + CELLS_WE;  // 632
constexpr int STAGE_CELLS = 2 * CELLS_NS + 2 * CELLS_WE;  // 720 cells

typedef unsigned long long u64;

// stencil coefficients, offsets -4..4, pre-scaled by 1/dx^2 and 1/dx
__device__ __constant__ float C2D[9] = {
    (float)(-1.0/560.0/100.0), (float)(8.0/315.0/100.0), (float)(-1.0/5.0/100.0),
    (float)(8.0/5.0/100.0),    (float)(-205.0/72.0/100.0), (float)(8.0/5.0/100.0),
    (float)(-1.0/5.0/100.0),   (float)(8.0/315.0/100.0),  (float)(-1.0/560.0/100.0)};
__device__ __constant__ float C1D[9] = {
    (float)(1.0/280.0/10.0), (float)(-4.0/105.0/10.0), (float)(1.0/5.0/10.0),
    (float)(-4.0/5.0/10.0),  0.0f,                     (float)(4.0/5.0/10.0),
    (float)(-1.0/5.0/10.0),  (float)(4.0/105.0/10.0),  (float)(-1.0/280.0/10.0)};

// ---------------- agent-scope accessors (coherent at Infinity Cache) -------
__device__ __forceinline__ u64 gload64(const u64* p) {
    return __hip_atomic_load(p, __ATOMIC_RELAXED, __HIP_MEMORY_SCOPE_AGENT);
}
__device__ __forceinline__ void gstore64(u64* p, u64 v) {
    __hip_atomic_store(p, v, __ATOMIC_RELAXED, __HIP_MEMORY_SCOPE_AGENT);
}

__device__ __forceinline__ float sigma_of(int d, int n, float smax) {
    float r = fmaxf(fmaxf((float)(PML - d) / (float)PML,
                          (float)(d - (n - 1 - PML)) / (float)PML), 0.0f);
    return smax * r * r;
}

// ---------------- setup: vmax -> sigma_max ----------------
__global__ void vmax_kernel(const float* __restrict__ vp, float* __restrict__ cst) {
    __shared__ float red[256];
    float m = 0.0f;
    for (int i = threadIdx.x; i < NY * NX; i += 256) m = fmaxf(m, vp[i]);
    red[threadIdx.x] = m;
    __syncthreads();
    for (int s2 = 128; s2 > 0; s2 >>= 1) {
        if (threadIdx.x < s2) red[threadIdx.x] = fmaxf(red[threadIdx.x], red[threadIdx.x + s2]);
        __syncthreads();
    }
    if (threadIdx.x == 0)
        cst[0] = 3.0f * red[0] * logf(1000.0f) / (2.0f * PML * DX);
}

// -- persistent kernel: fused-weight convolution, publish-early, 1 barrier ---
__global__ __launch_bounds__(THREADS) void persist_kernel(
    const float* __restrict__ vp, const float* __restrict__ src,
    const int* __restrict__ src_loc, const int* __restrict__ rec_loc,
    float* __restrict__ out, u64* __restrict__ stage,
    const float* __restrict__ cst) {

    __shared__ float uT[2][UTSZ];          // u, x-major (column role reads)
    __shared__ float uR[2][URSZ];          // u, y-major (row role reads)
    __shared__ float pyT[2][PTSZ];         // py, x-major
    __shared__ float pxR[2][PXSZ];         // px, y-major
    __shared__ float byS[BYW], bymS[BYW], bxS[BXW], bxmS[BXW];
    __shared__ float srcS[NT];             // this shot's source wavelet

    const int tid = threadIdx.x;
    const int bid = blockIdx.x;
    const int sh  = bid / (NTY * NTX);
    const int tr  = bid - sh * (NTY * NTX);
    const int tyi = tr / NTX, txi = tr - tyi * NTX;
    const int y0 = tyi * TY, x0 = txi * TX;
    const int rows = min(TY, NYP - y0), cols = min(TX, NXP - x0);
    const float smax = cst[0];

    // zero LDS state (domain-boundary halos stay 0 forever)
    for (int i = tid; i < 2 * UTSZ; i += THREADS) ((float*)uT)[i] = 0.0f;
    for (int i = tid; i < 2 * URSZ; i += THREADS) ((float*)uR)[i] = 0.0f;
    for (int i = tid; i < 2 * PTSZ; i += THREADS) ((float*)pyT)[i] = 0.0f;
    for (int i = tid; i < 2 * PXSZ; i += THREADS) ((float*)pxR)[i] = 0.0f;

    if (tid < BYW) {
        int yy = y0 - 4 + tid;
        if (yy >= 0 && yy < NYP) {
            float b = __expf(-sigma_of(yy, NYP, smax) * DT);
            byS[tid] = b; bymS[tid] = b - 1.0f;
        } else { byS[tid] = 0.0f; bymS[tid] = 0.0f; }
    }
    if (tid < BXW) {
        int xx = x0 - 4 + tid;
        if (xx >= 0 && xx < NXP) {
            float b = __expf(-sigma_of(xx, NXP, smax) * DT);
            bxS[tid] = b; bxmS[tid] = b - 1.0f;
        } else { bxS[tid] = 0.0f; bxmS[tid] = 0.0f; }
    }

    // lane-pair cell mapping: threads 2c (role 0: column) / 2c+1 (role 1: row)
    const int role = tid & 1;
    const int cell = tid >> 1;
    const bool hasTask = (tid < 2 * rows * cols);
    const int y = hasTask ? cell / cols : 0;
    const int x = hasTask ? cell - y * cols : 0;

    // per-thread t-invariant physics coefficients (role 0 only)
    float e_r = 0.0f, d_r = 0.0f, Av_r = 0.0f, Bv_r = 0.0f;
    if (hasTask && role == 0) {
        int gy = y0 + y, gx = x0 + x;
        int vy = min(max(gy - PML, 0), NY - 1), vx = min(max(gx - PML, 0), NX - 1);
        float v = vp[vy * NX + vx];
        e_r = DT2 * v * v;
        float syv = sigma_of(gy, NYP, smax), sxv = sigma_of(gx, NXP, smax);
        d_r  = 1.0f / (1.0f + 0.5f * (syv + sxv) * DT);
        Av_r = 2.0f - syv * sxv * DT2;
        Bv_r = 1.0f - 0.5f * (syv + sxv) * DT;
    }

    // source (NSRC == 1 per shot); stage wavelet into LDS
    const int sy = src_loc[sh * 2 + 0] + PML, sx = src_loc[sh * 2 + 1] + PML;
    const bool ownSrc = (sy >= y0 && sy < y0 + rows && sx >= x0 && sx < x0 + cols);
    const bool isSrc = hasTask && (role == 0) && ownSrc &&
                       (y == sy - y0) && (x == sx - x0);
    if (ownSrc)
        for (int i = tid; i < NT; i += THREADS) srcS[i] = src[sh * NT + i];

    // receiver: thread tid handles global receiver tid (<=1 per thread)
    int recLds = -1, recOut = 0;
    if (tid < S * NREC) {
        int rs = tid / NREC, rr2 = tid - rs * NREC;
        int ry = rec_loc[(rs * NREC + rr2) * 2 + 0] + PML;
        int rx = rec_loc[(rs * NREC + rr2) * 2 + 1] + PML;
        if (rs == sh && ry >= y0 && ry < y0 + rows && rx >= x0 && rx < x0 + cols) {
            recLds = (ry - y0) * URS + (rx - x0 + 8);    // in uR (y-major)
            recOut = rs * NT * NREC + rr2;
        }
    }

    const int bN = (tyi > 0)       ? bid - NTX : -1;
    const int bS = (tyi < NTY - 1) ? bid + NTX : -1;
    const int bW = (txi > 0)       ? bid - 1   : -1;
    const int bE = (txi < NTX - 1) ? bid + 1   : -1;

    const int nNS = 8 * cols, nWE = rows * 8;
    const int nTot = 2 * nNS + 2 * nWE;       // <= 720 <= THREADS

    // ---- single halo-read descriptor per thread (t-invariant) ----
    // N/S halo rows feed the column role -> uT; W/E cols -> uR.
    int hOff = -1, hSrc = 0, hTgt = 0;
    if (tid < nTot) {
        int j = tid, nb = -1, o = 0, off = -1, tgt = 0;
        if (j < nNS) {                         // from N neighbor's S strip
            nb = bN;
            int r2 = j / cols, c2 = j - r2 * cols;
            o = OFF_S + r2 * TX + c2;          // N nb always has rows==TY>=8
            off = c2 * UTS + r2; tgt = 0;
        } else if ((j -= nNS) < nNS) {         // from S neighbor's N strip
            nb = bS;
            int r2 = j / cols, c2 = j - r2 * cols;
            if (nb >= 0) {
                int rowsS = min(TY, NYP - (y0 + TY));
                if (r2 >= rowsS) nb = -1;      // out-of-domain: stays 0
            }
            o = OFF_N + r2 * TX + c2;
            off = c2 * UTS + (8 + rows + r2); tgt = 0;
        } else if ((j -= nNS) < nWE) {         // from W neighbor's E strip
            nb = bW;
            o = OFF_E + j;
            off = (j >> 3) * URS + (j & 7); tgt = 1;
        } else {                               // from E neighbor's W strip
            j -= nWE;
            nb = bE;
            o = OFF_W + j;
            off = (j >> 3) * URS + 8 + cols + (j & 7); tgt = 1;
        }
        if (nb >= 0) { hOff = off; hTgt = tgt; hSrc = nb * 2 * STAGE_CELLS + o; }
    }
    const bool nv = (hOff >= 0);
    const u64* sA = stage + hSrc;

    // ---- strip-push cell offsets (role 0 only, t-invariant) ----
    int aN = -1, aS = -1, aW = -1, aE = -1;
    if (hasTask && role == 0) {
        if (y < 8)          aN = OFF_N + y * TX + x;
        if (y >= rows - 8)  aS = OFF_S + (y - (rows - 8)) * TX + x;
        if (x < 8)          aW = OFF_W + y * 8 + x;
        if (x >= cols - 8)  aE = OFF_E + y * 8 + (x - (cols - 8));
    }

    // prologue: publish u(0)=0 cells with tag=1 into parity-0 slot
    {
        const u64 PK0 = ((u64)1 << 32);
        u64* s0 = stage + (size_t)(bid * 2 + 0) * STAGE_CELLS;
        if (aN >= 0) gstore64(s0 + aN, PK0);
        if (aS >= 0) gstore64(s0 + aS, PK0);
        if (aW >= 0) gstore64(s0 + aW, PK0);
        if (aE >= 0) gstore64(s0 + aE, PK0);
    }
    __syncthreads();

    // ---- fused per-thread convolution weights (t-invariant) ----
    // lap_partial = sum_n wU[n]*up[n] + sum_k cbp[k]*pOld[k]
    //   wU[n] = C2D[n-4] (4<=n<=12)  +  sum_k C1D[k]*bbm[k]*C1D[n-k]
    //   cbp[k] = C1D[k]*bb[k]        (C1D[4]==0 excludes k=4 automatically)
    float wU[17], cbp[9];
    float bb0 = 0, bbm0 = 0, bb4 = 0, bbm4 = 0, bb8 = 0, bbm8 = 0;
    {
        float tb[9], tbm[9];
#pragma unroll
        for (int j = 0; j < 9; j++) {
            tb[j]  = hasTask ? (role ? bxS[x + j]  : byS[y + j])  : 0.0f;
            tbm[j] = hasTask ? (role ? bxmS[x + j] : bymS[y + j]) : 0.0f;
        }
#pragma unroll
        for (int n = 0; n < 17; n++) {
            float w = (n >= 4 && n <= 12) ? C2D[n - 4] : 0.0f;
#pragma unroll
            for (int k = 0; k < 9; k++) {
                int m = n - k;
                if (m >= 0 && m < 9)
                    w = fmaf(C1D[k] * tbm[k], C1D[m], w);
            }
            wU[n] = w;
        }
#pragma unroll
        for (int k = 0; k < 9; k++) cbp[k] = C1D[k] * tb[k];
        bb0 = tb[0]; bbm0 = tbm[0];
        bb4 = tb[4]; bbm4 = tbm[4];
        bb8 = tb[8]; bbm8 = tbm[8];
    }

    // prefetch for t=0 (parity-0 slot)
    u64 pf = nv ? gload64(sA) : 0;

    float u_curr = 0.0f, u_prev = 0.0f;        // this cell's u(t), u(t-1)

    int pa = 0;
    for (int t = 0; t < NT; t++) {
        const int par = t & 1;                 // slot holding u(t) strips
        float* uTc = uT[pa];       float* uRc = uR[pa];
        float* uTn = uT[pa ^ 1];   float* uRn = uR[pa ^ 1];
        const float* pyO = pyT[pa]; float* pyN = pyT[pa ^ 1];
        const float* pxO = pxR[pa]; float* pxN = pxR[pa ^ 1];

        // ---- 1. spin on prefetched packed cell; write halo to LDS ----
        if (nv) {
            const int need = t + 1;
            const u64* sp = sA + (size_t)par * STAGE_CELLS;
            while ((int)(pf >> 32) < need) pf = gload64(sp);
            (hTgt ? uRc : uTc)[hOff] = __uint_as_float((unsigned)pf);
        }
        __syncthreads();                       // the ONLY barrier per step

        // ---- 2. receivers sample u(t) = un(t-1) ----
        if (t > 0 && recLds >= 0) out[recOut + (t - 1) * NREC] = uRc[recLds];

        // ---- 3. fused conv -> publish ASAP; state writes in the tail ----
        u64* sb = stage + (size_t)(bid * 2 + (par ^ 1)) * STAGE_CELLS;
        if (hasTask) {
            const float* uSrc = role ? &uRc[y * URS + x] : &uTc[x * UTS + y];
            const float* pSrc = role ? &pxO[y * PXS + x] : &pyO[x * PTS + y];
            float* pDst = role ? &pxN[y * PXS + x] : &pyN[x * PTS + y];
            float* uDst = role ? &uRn[y * URS + x + 8] : &uTn[x * UTS + y + 8];

            float up[17];
#pragma unroll
            for (int j = 0; j < 17; j++)
                up[j] = (j == 8) ? u_curr : uSrc[j];
            float pO[9];
#pragma unroll
            for (int k = 0; k < 9; k++) pO[k] = pSrc[k];

            // 26-FMA fused dot in 4 independent chains (short dep depth)
            float a0 = 0.0f, a1 = 0.0f, a2 = 0.0f, a3 = 0.0f;
#pragma unroll
            for (int n = 0; n < 16; n += 4) {
                a0 = fmaf(wU[n],     up[n],     a0);
                a1 = fmaf(wU[n + 1], up[n + 1], a1);
                a2 = fmaf(wU[n + 2], up[n + 2], a2);
                a3 = fmaf(wU[n + 3], up[n + 3], a3);
            }
            a0 = fmaf(wU[16], up[16], a0);
#pragma unroll
            for (int k = 0; k < 8; k += 4) {
                a0 = fmaf(cbp[k],     pO[k],     a0);
                a1 = fmaf(cbp[k + 1], pO[k + 1], a1);
                a2 = fmaf(cbp[k + 2], pO[k + 2], a2);
                a3 = fmaf(cbp[k + 3], pO[k + 3], a3);
            }
            a1 = fmaf(cbp[8], pO[8], a1);
            const float partial = (a0 + a1) + (a2 + a3);
            const float other = __shfl_xor(partial, 1);  // pair exchange

            float unv = 0.0f;
            if (role == 0) {
                const float lap = partial + other;
                const float f = isSrc ? srcS[t] : 0.0f;
                unv = (Av_r * u_curr - Bv_r * u_prev + e_r * (lap + f)) * d_r;
                // publish immediately: {u(t+1), tag=t+2} from register
                const u64 pk = ((u64)(unsigned)(t + 2) << 32) |
                               (u64)__float_as_uint(unv);
                if (aN >= 0) gstore64(sb + aN, pk);
                if (aS >= 0) gstore64(sb + aS, pk);
                if (aW >= 0) gstore64(sb + aW, pk);
                if (aE >= 0) gstore64(sb + aE, pk);
            }
            const float got = __shfl_xor(unv, 1);        // unv to role 1
            const float u_new = role ? got : unv;

            // ---- tail (after publish): p-state + u-state LDS writes ----
            uDst[0] = u_new;
            {
                float d1u4 = 0.0f;
#pragma unroll
                for (int m = 0; m < 9; m++) d1u4 = fmaf(C1D[m], up[4 + m], d1u4);
                pDst[4] = fmaf(bb4, pO[4], bbm4 * d1u4);
            }
            const int lo = role ? x : y;
            const int hiLim = role ? cols : rows;
            if (lo < 4) {
                float d1u0 = 0.0f;
#pragma unroll
                for (int m = 0; m < 9; m++) d1u0 = fmaf(C1D[m], up[m], d1u0);
                pDst[0] = fmaf(bb0, pO[0], bbm0 * d1u0);
            }
            if (lo >= hiLim - 4) {
                float d1u8 = 0.0f;
#pragma unroll
                for (int m = 0; m < 9; m++) d1u8 = fmaf(C1D[m], up[8 + m], d1u8);
                pDst[8] = fmaf(bb8, pO[8], bbm8 * d1u8);
            }

            u_prev = u_curr; u_curr = u_new;
        }

        // ---- 4. prefetch next slot (overlaps MALL RT with loop tail) ----
        if (nv) pf = gload64(sA + (size_t)(par ^ 1) * STAGE_CELLS);

        pa ^= 1;
    }

    // epilogue: sample the last wavefield u(NT) = un(NT-1)
    __syncthreads();
    if (recLds >= 0) out[recOut + (NT - 1) * NREC] = uR[pa][recLds];
}

// ---------------- host launch ----------------
extern "C" void kernel_launch(void* const* d_in, const int* in_sizes, int n_in,
                              void* d_out, int out_size, void* d_ws, size_t ws_size,
                              hipStream_t stream) {
    const float* vp = (const float*)d_in[0];
    const float* src = (const float*)d_in[1];
    const int* src_loc = (const int*)d_in[2];
    const int* rec_loc = (const int*)d_in[3];
    float* out = (float*)d_out;

    float* ws = (float*)d_ws;
    float* cst = ws;                           // 32 floats (keeps stage 8B-aligned)
    u64* stage = (u64*)(ws + 32);              // NBLKS*2*STAGE_CELLS packed cells

    // zero cst + stage (tags=0; prologue publishes tag=1 cells into slot 0)
    hipMemsetAsync(d_ws, 0,
                   (size_t)32 * sizeof(float) +
                   (size_t)NBLKS * 2 * STAGE_CELLS * sizeof(u64),
                   stream);
    vmax_kernel<<<1, 256, 0, stream>>>(vp, cst);
    persist_kernel<<<NBLKS, THREADS, 0, stream>>>(
        vp, src, src_loc, rec_loc, out, stage, cst);
}

// Round 15
// 637.889 us; speedup vs baseline: 1.7740x; 1.1202x over previous
//
#include <hip/hip_runtime.h>

// ---------------- problem constants ----------------
constexpr int NY = 100, NX = 200;
constexpr int PML = 35;
constexpr int NYP = 170, NXP = 270;          // padded grid
constexpr int S = 2, NREC = 100, NT = 300;
constexpr float DX = 10.0f, DT = 1e-3f, DT2 = DT * DT;

// tiling: 2 shots x 16x8 tiles -> 256 blocks (one per CU)
constexpr int NTY = 16, NTX = 8;
constexpr int TY = 11, TX = 34;              // nominal tile (last row/col smaller)
constexpr int NBLKS = S * NTY * NTX;         // 256
constexpr int THREADS = 768;                 // 2 threads per cell, 12 waves/CU

// dual-orientation LDS (odd strides -> full bank spread; every hot access is
// base[j] with compile-time j -> ds_read offset: immediates, no address VALU)
constexpr int UTS = 35;                      // uT stride: uT[x][y+8], slots 0..26
constexpr int UTSZ = TX * UTS;               // 1190
constexpr int URS = 51;                      // uR stride: uR[y][x+8], slots 0..49
constexpr int URSZ = TY * URS;               // 561
constexpr int PTS = 19;                      // pyT stride: pyT[x][y+4], slots 0..18
constexpr int PTSZ = TX * PTS;               // 646
constexpr int PXS = 43;                      // pxR stride: pxR[y][x+4], slots 0..41
constexpr int PXSZ = TY * PXS;               // 473
constexpr int BYW = TY + 8;                  // 19
constexpr int BXW = TX + 8;                  // 42

// packed strips: each halo cell is 8B {float value, int tag} (single-copy atomic)
constexpr int CELLS_NS = 8 * TX;             // 272
constexpr int CELLS_WE = TY * 8;             // 88
constexpr int OFF_N = 0;
constexpr int OFF_S = CELLS_NS;              // 272
constexpr int OFF_W = 2 * CELLS_NS;          // 544
constexpr int OFF_E = 2 * CELLS_NS + CELLS_WE;  // 632
constexpr int STAGE_CELLS = 2 * CELLS_NS + 2 * CELLS_WE;  // 720 cells

typedef unsigned long long u64;

// stencil coefficients, offsets -4..4, pre-scaled by 1/dx^2 and 1/dx
__device__ __constant__ float C2D[9] = {
    (float)(-1.0/560.0/100.0), (float)(8.0/315.0/100.0), (float)(-1.0/5.0/100.0),
    (float)(8.0/5.0/100.0),    (float)(-205.0/72.0/100.0), (float)(8.0/5.0/100.0),
    (float)(-1.0/5.0/100.0),   (float)(8.0/315.0/100.0),  (float)(-1.0/560.0/100.0)};
__device__ __constant__ float C1D[9] = {
    (float)(1.0/280.0/10.0), (float)(-4.0/105.0/10.0), (float)(1.0/5.0/10.0),
    (float)(-4.0/5.0/10.0),  0.0f,                     (float)(4.0/5.0/10.0),
    (float)(-1.0/5.0/10.0),  (float)(4.0/105.0/10.0),  (float)(-1.0/280.0/10.0)};

// ---------------- agent-scope accessors (coherent at Infinity Cache) -------
__device__ __forceinline__ u64 gload64(const u64* p) {
    return __hip_atomic_load(p, __ATOMIC_RELAXED, __HIP_MEMORY_SCOPE_AGENT);
}
__device__ __forceinline__ void gstore64(u64* p, u64 v) {
    __hip_atomic_store(p, v, __ATOMIC_RELAXED, __HIP_MEMORY_SCOPE_AGENT);
}

__device__ __forceinline__ float sigma_of(int d, int n, float smax) {
    float r = fmaxf(fmaxf((float)(PML - d) / (float)PML,
                          (float)(d - (n - 1 - PML)) / (float)PML), 0.0f);
    return smax * r * r;
}

// ---------------- setup: vmax -> sigma_max ----------------
__global__ void vmax_kernel(const float* __restrict__ vp, float* __restrict__ cst) {
    __shared__ float red[256];
    float m = 0.0f;
    for (int i = threadIdx.x; i < NY * NX; i += 256) m = fmaxf(m, vp[i]);
    red[threadIdx.x] = m;
    __syncthreads();
    for (int s2 = 128; s2 > 0; s2 >>= 1) {
        if (threadIdx.x < s2) red[threadIdx.x] = fmaxf(red[threadIdx.x], red[threadIdx.x + s2]);
        __syncthreads();
    }
    if (threadIdx.x == 0)
        cst[0] = 3.0f * red[0] * logf(1000.0f) / (2.0f * PML * DX);
}

// -- persistent kernel: fused conv, both-role unv (no return shuffle) --------
__global__ __launch_bounds__(THREADS) void persist_kernel(
    const float* __restrict__ vp, const float* __restrict__ src,
    const int* __restrict__ src_loc, const int* __restrict__ rec_loc,
    float* __restrict__ out, u64* __restrict__ stage,
    const float* __restrict__ cst) {

    __shared__ float uT[2][UTSZ];          // u, x-major (column role reads)
    __shared__ float uR[2][URSZ];          // u, y-major (row role reads)
    __shared__ float pyT[2][PTSZ];         // py, x-major
    __shared__ float pxR[2][PXSZ];         // px, y-major
    __shared__ float byS[BYW], bymS[BYW], bxS[BXW], bxmS[BXW];
    __shared__ float srcS[NT];             // this shot's source wavelet

    const int tid = threadIdx.x;
    const int bid = blockIdx.x;
    const int sh  = bid / (NTY * NTX);
    const int tr  = bid - sh * (NTY * NTX);
    const int tyi = tr / NTX, txi = tr - tyi * NTX;
    const int y0 = tyi * TY, x0 = txi * TX;
    const int rows = min(TY, NYP - y0), cols = min(TX, NXP - x0);
    const float smax = cst[0];

    // zero LDS state (domain-boundary halos stay 0 forever)
    for (int i = tid; i < 2 * UTSZ; i += THREADS) ((float*)uT)[i] = 0.0f;
    for (int i = tid; i < 2 * URSZ; i += THREADS) ((float*)uR)[i] = 0.0f;
    for (int i = tid; i < 2 * PTSZ; i += THREADS) ((float*)pyT)[i] = 0.0f;
    for (int i = tid; i < 2 * PXSZ; i += THREADS) ((float*)pxR)[i] = 0.0f;

    if (tid < BYW) {
        int yy = y0 - 4 + tid;
        if (yy >= 0 && yy < NYP) {
            float b = __expf(-sigma_of(yy, NYP, smax) * DT);
            byS[tid] = b; bymS[tid] = b - 1.0f;
        } else { byS[tid] = 0.0f; bymS[tid] = 0.0f; }
    }
    if (tid < BXW) {
        int xx = x0 - 4 + tid;
        if (xx >= 0 && xx < NXP) {
            float b = __expf(-sigma_of(xx, NXP, smax) * DT);
            bxS[tid] = b; bxmS[tid] = b - 1.0f;
        } else { bxS[tid] = 0.0f; bxmS[tid] = 0.0f; }
    }

    // lane-pair cell mapping: threads 2c (role 0: column) / 2c+1 (role 1: row)
    const int role = tid & 1;
    const int cell = tid >> 1;
    const bool hasTask = (tid < 2 * rows * cols);
    const int y = hasTask ? cell / cols : 0;
    const int x = hasTask ? cell - y * cols : 0;

    // per-thread t-invariant physics coefficients (BOTH roles: each computes
    // unv redundantly, bitwise-identically -> no return shuffle needed)
    float e_r = 0.0f, d_r = 0.0f, Av_r = 0.0f, Bv_r = 0.0f;
    if (hasTask) {
        int gy = y0 + y, gx = x0 + x;
        int vy = min(max(gy - PML, 0), NY - 1), vx = min(max(gx - PML, 0), NX - 1);
        float v = vp[vy * NX + vx];
        e_r = DT2 * v * v;
        float syv = sigma_of(gy, NYP, smax), sxv = sigma_of(gx, NXP, smax);
        d_r  = 1.0f / (1.0f + 0.5f * (syv + sxv) * DT);
        Av_r = 2.0f - syv * sxv * DT2;
        Bv_r = 1.0f - 0.5f * (syv + sxv) * DT;
    }

    // source (NSRC == 1 per shot); stage wavelet into LDS
    const int sy = src_loc[sh * 2 + 0] + PML, sx = src_loc[sh * 2 + 1] + PML;
    const bool ownSrc = (sy >= y0 && sy < y0 + rows && sx >= x0 && sx < x0 + cols);
    const bool isSrc = hasTask && ownSrc && (y == sy - y0) && (x == sx - x0);
    if (ownSrc)
        for (int i = tid; i < NT; i += THREADS) srcS[i] = src[sh * NT + i];

    // receiver: thread tid handles global receiver tid (<=1 per thread)
    int recLds = -1, recOut = 0;
    if (tid < S * NREC) {
        int rs = tid / NREC, rr2 = tid - rs * NREC;
        int ry = rec_loc[(rs * NREC + rr2) * 2 + 0] + PML;
        int rx = rec_loc[(rs * NREC + rr2) * 2 + 1] + PML;
        if (rs == sh && ry >= y0 && ry < y0 + rows && rx >= x0 && rx < x0 + cols) {
            recLds = (ry - y0) * URS + (rx - x0 + 8);    // in uR (y-major)
            recOut = rs * NT * NREC + rr2;
        }
    }

    const int bN = (tyi > 0)       ? bid - NTX : -1;
    const int bS = (tyi < NTY - 1) ? bid + NTX : -1;
    const int bW = (txi > 0)       ? bid - 1   : -1;
    const int bE = (txi < NTX - 1) ? bid + 1   : -1;

    const int nNS = 8 * cols, nWE = rows * 8;
    const int nTot = 2 * nNS + 2 * nWE;       // <= 720 <= THREADS

    // ---- single halo-read descriptor per thread (t-invariant) ----
    // N/S halo rows feed the column role -> uT; W/E cols -> uR.
    int hOff = -1, hSrc = 0, hTgt = 0;
    if (tid < nTot) {
        int j = tid, nb = -1, o = 0, off = -1, tgt = 0;
        if (j < nNS) {                         // from N neighbor's S strip
            nb = bN;
            int r2 = j / cols, c2 = j - r2 * cols;
            o = OFF_S + r2 * TX + c2;          // N nb always has rows==TY>=8
            off = c2 * UTS + r2; tgt = 0;
        } else if ((j -= nNS) < nNS) {         // from S neighbor's N strip
            nb = bS;
            int r2 = j / cols, c2 = j - r2 * cols;
            if (nb >= 0) {
                int rowsS = min(TY, NYP - (y0 + TY));
                if (r2 >= rowsS) nb = -1;      // out-of-domain: stays 0
            }
            o = OFF_N + r2 * TX + c2;
            off = c2 * UTS + (8 + rows + r2); tgt = 0;
        } else if ((j -= nNS) < nWE) {         // from W neighbor's E strip
            nb = bW;
            o = OFF_E + j;
            off = (j >> 3) * URS + (j & 7); tgt = 1;
        } else {                               // from E neighbor's W strip
            j -= nWE;
            nb = bE;
            o = OFF_W + j;
            off = (j >> 3) * URS + 8 + cols + (j & 7); tgt = 1;
        }
        if (nb >= 0) { hOff = off; hTgt = tgt; hSrc = nb * 2 * STAGE_CELLS + o; }
    }
    const bool nv = (hOff >= 0);
    const u64* sA = stage + hSrc;

    // ---- strip-push cell offsets (role 0 only, t-invariant) ----
    int aN = -1, aS = -1, aW = -1, aE = -1;
    if (hasTask && role == 0) {
        if (y < 8)          aN = OFF_N + y * TX + x;
        if (y >= rows - 8)  aS = OFF_S + (y - (rows - 8)) * TX + x;
        if (x < 8)          aW = OFF_W + y * 8 + x;
        if (x >= cols - 8)  aE = OFF_E + y * 8 + (x - (cols - 8));
    }

    // prologue: publish u(0)=0 cells with tag=1 into parity-0 slot
    {
        const u64 PK0 = ((u64)1 << 32);
        u64* s0 = stage + (size_t)(bid * 2 + 0) * STAGE_CELLS;
        if (aN >= 0) gstore64(s0 + aN, PK0);
        if (aS >= 0) gstore64(s0 + aS, PK0);
        if (aW >= 0) gstore64(s0 + aW, PK0);
        if (aE >= 0) gstore64(s0 + aE, PK0);
    }
    __syncthreads();

    // ---- fused per-thread convolution weights (t-invariant) ----
    // lap_partial = sum_n wU[n]*up[n] + sum_k cbp[k]*pOld[k]
    //   wU[n] = C2D[n-4] (4<=n<=12)  +  sum_k C1D[k]*bbm[k]*C1D[n-k]
    //   cbp[k] = C1D[k]*bb[k]        (C1D[4]==0 excludes k=4 automatically)
    float wU[17], cbp[9];
    float bb0 = 0, bbm0 = 0, bb4 = 0, bbm4 = 0, bb8 = 0, bbm8 = 0;
    {
        float tb[9], tbm[9];
#pragma unroll
        for (int j = 0; j < 9; j++) {
            tb[j]  = hasTask ? (role ? bxS[x + j]  : byS[y + j])  : 0.0f;
            tbm[j] = hasTask ? (role ? bxmS[x + j] : bymS[y + j]) : 0.0f;
        }
#pragma unroll
        for (int n = 0; n < 17; n++) {
            float w = (n >= 4 && n <= 12) ? C2D[n - 4] : 0.0f;
#pragma unroll
            for (int k = 0; k < 9; k++) {
                int m = n - k;
                if (m >= 0 && m < 9)
                    w = fmaf(C1D[k] * tbm[k], C1D[m], w);
            }
            wU[n] = w;
        }
#pragma unroll
        for (int k = 0; k < 9; k++) cbp[k] = C1D[k] * tb[k];
        bb0 = tb[0]; bbm0 = tbm[0];
        bb4 = tb[4]; bbm4 = tbm[4];
        bb8 = tb[8]; bbm8 = tbm[8];
    }

    // prefetch for t=0 (parity-0 slot)
    u64 pf = nv ? gload64(sA) : 0;

    float u_curr = 0.0f, u_prev = 0.0f;        // this cell's u(t), u(t-1)

    int pa = 0;
    for (int t = 0; t < NT; t++) {
        const int par = t & 1;                 // slot holding u(t) strips
        float* uTc = uT[pa];       float* uRc = uR[pa];
        float* uTn = uT[pa ^ 1];   float* uRn = uR[pa ^ 1];
        const float* pyO = pyT[pa]; float* pyN = pyT[pa ^ 1];
        const float* pxO = pxR[pa]; float* pxN = pxR[pa ^ 1];

        // ---- 1. spin on prefetched packed cell; write halo to LDS ----
        if (nv) {
            const int need = t + 1;
            const u64* sp = sA + (size_t)par * STAGE_CELLS;
            while ((int)(pf >> 32) < need) pf = gload64(sp);
            (hTgt ? uRc : uTc)[hOff] = __uint_as_float((unsigned)pf);
        }
        __syncthreads();                       // the ONLY barrier per step

        // ---- 2. fused conv -> publish ASAP ----
        u64* sb = stage + (size_t)(bid * 2 + (par ^ 1)) * STAGE_CELLS;
        float up[17], pO[9], u_new = 0.0f;
        if (hasTask) {
            const float* uSrc = role ? &uRc[y * URS + x] : &uTc[x * UTS + y];
            const float* pSrc = role ? &pxO[y * PXS + x] : &pyO[x * PTS + y];

#pragma unroll
            for (int j = 0; j < 17; j++)
                up[j] = (j == 8) ? u_curr : uSrc[j];
#pragma unroll
            for (int k = 0; k < 9; k++) pO[k] = pSrc[k];

            // 26-FMA fused dot in 4 independent chains (short dep depth)
            float a0 = 0.0f, a1 = 0.0f, a2 = 0.0f, a3 = 0.0f;
#pragma unroll
            for (int n = 0; n < 16; n += 4) {
                a0 = fmaf(wU[n],     up[n],     a0);
                a1 = fmaf(wU[n + 1], up[n + 1], a1);
                a2 = fmaf(wU[n + 2], up[n + 2], a2);
                a3 = fmaf(wU[n + 3], up[n + 3], a3);
            }
            a0 = fmaf(wU[16], up[16], a0);
#pragma unroll
            for (int k = 0; k < 8; k += 4) {
                a0 = fmaf(cbp[k],     pO[k],     a0);
                a1 = fmaf(cbp[k + 1], pO[k + 1], a1);
                a2 = fmaf(cbp[k + 2], pO[k + 2], a2);
                a3 = fmaf(cbp[k + 3], pO[k + 3], a3);
            }
            a1 = fmaf(cbp[8], pO[8], a1);
            const float partial = (a0 + a1) + (a2 + a3);
            const float other = __shfl_xor(partial, 1);  // the ONLY shuffle

            // both roles compute unv (bitwise identical: a+b == b+a)
            const float lap = partial + other;
            const float f = isSrc ? srcS[t] : 0.0f;
            u_new = (Av_r * u_curr - Bv_r * u_prev + e_r * (lap + f)) * d_r;

            // publish immediately (role-1 lanes have a* == -1: predicated off)
            const u64 pk = ((u64)(unsigned)(t + 2) << 32) |
                           (u64)__float_as_uint(u_new);
            if (aN >= 0) gstore64(sb + aN, pk);
            if (aS >= 0) gstore64(sb + aS, pk);
            if (aW >= 0) gstore64(sb + aW, pk);
            if (aE >= 0) gstore64(sb + aE, pk);
        }

        // ---- 3. prefetch next slot early (hides RT under tail work) ----
        if (nv) pf = gload64(sA + (size_t)(par ^ 1) * STAGE_CELLS);

        // ---- 4. tail: p-state + u-state LDS writes ----
        if (hasTask) {
            float* pDst = role ? &pxR[pa ^ 1][y * PXS + x] : &pyT[pa ^ 1][x * PTS + y];
            float* uDst = role ? &uRn[y * URS + x + 8] : &uTn[x * UTS + y + 8];
            uDst[0] = u_new;
            {
                float d1u4 = 0.0f;
#pragma unroll
                for (int m = 0; m < 9; m++) d1u4 = fmaf(C1D[m], up[4 + m], d1u4);
                pDst[4] = fmaf(bb4, pO[4], bbm4 * d1u4);
            }
            const int lo = role ? x : y;
            const int hiLim = role ? cols : rows;
            if (lo < 4) {
                float d1u0 = 0.0f;
#pragma unroll
                for (int m = 0; m < 9; m++) d1u0 = fmaf(C1D[m], up[m], d1u0);
                pDst[0] = fmaf(bb0, pO[0], bbm0 * d1u0);
            }
            if (lo >= hiLim - 4) {
                float d1u8 = 0.0f;
#pragma unroll
                for (int m = 0; m < 9; m++) d1u8 = fmaf(C1D[m], up[8 + m], d1u8);
                pDst[8] = fmaf(bb8, pO[8], bbm8 * d1u8);
            }
            u_prev = u_curr; u_curr = u_new;
        }

        // ---- 5. receivers sample u(t) = un(t-1) (off the critical chain) --
        if (t > 0 && recLds >= 0) out[recOut + (t - 1) * NREC] = uRc[recLds];

        pa ^= 1;
    }

    // epilogue: sample the last wavefield u(NT) = un(NT-1)
    __syncthreads();
    if (recLds >= 0) out[recOut + (NT - 1) * NREC] = uR[pa][recLds];
}

// ---------------- host launch ----------------
extern "C" void kernel_launch(void* const* d_in, const int* in_sizes, int n_in,
                              void* d_out, int out_size, void* d_ws, size_t ws_size,
                              hipStream_t stream) {
    const float* vp = (const float*)d_in[0];
    const float* src = (const float*)d_in[1];
    const int* src_loc = (const int*)d_in[2];
    const int* rec_loc = (const int*)d_in[3];
    float* out = (float*)d_out;

    float* ws = (float*)d_ws;
    float* cst = ws;                           // 32 floats (keeps stage 8B-aligned)
    u64* stage = (u64*)(ws + 32);              // NBLKS*2*STAGE_CELLS packed cells

    // zero cst + stage (tags=0; prologue publishes tag=1 cells into slot 0)
    hipMemsetAsync(d_ws, 0,
                   (size_t)32 * sizeof(float) +
                   (size_t)NBLKS * 2 * STAGE_CELLS * sizeof(u64),
                   stream);
    vmax_kernel<<<1, 256, 0, stream>>>(vp, cst);
    persist_kernel<<<NBLKS, THREADS, 0, stream>>>(
        vp, src, src_loc, rec_loc, out, stage, cst);
}